// Round 8
// baseline (105.301 us; speedup 1.0000x reference)
//
#include <hip/hip_runtime.h>

// SoftFAPELoss: B=8, N=M=4096, D=3. Exact two-pass shifted softmax,
// packed-FP32 (v_pk_*) hot loop, 8 rows per lane.
// softfape_main: grid 512 x 512 thr (8 waves). Block = (b, 512-row group,
//   1/8th of M = 512 q). q's transformed+prescaled into 8 KB LDS
//   (q.xyz = -2c*y, q.w = c*|y|^2); wave scans a 64-q slice via wave-uniform
//   ds_read_b128 broadcast; lane owns 8 rows as 4 float2 packs.
//   Pass 1: A = q.p + c|q|^2 (3 pk_fma), minA = pk_min.  Block merge of
//     minA across 8 waves -> uniform per-row shift sh (A-units).
//   Pass 2: arg = sh - A <= 0 (pk), w = exp2(arg) per half, L += w (pk),
//     SA = pk_fma(w, arg, SA). Chunk-min term -> w = 1 exactly, so L >= 1:
//     underflow structurally impossible. Same-shift wave partials merge with
//     plain adds. Chunk partial (m_d = sh + c|p|^2, L, SA) -> Pg.
// softfape_finalize: merge 8 chunk partials per row with exp2(m - m_i) <= 1
//   factors; wd = m - SA/L; block-reduce; atomicAdd * T*ln2/(B*N).

#define B_    8
#define N_    4096
#define M_    4096
#define NWAVE 8
#define BLOCK (NWAVE * 64)        // 512
#define ROWS  512                 // rows per block (8 per lane)
#define MSPL  8                   // M split across blocks
#define QCH   (M_ / MSPL)         // 512 q per block
#define WQ    (QCH / NWAVE)       // 64 q per wave
#define LOG2E 1.4426950408889634f
#define LN2   0.6931471805599453f
#define BIGF  3.0e38f

typedef float v2f __attribute__((ext_vector_type(2)));

__global__ __launch_bounds__(BLOCK, 6) void softfape_main(
    const float* __restrict__ X_pred, const float* __restrict__ X_true,
    const float* __restrict__ R_pred, const float* __restrict__ t_pred,
    const float* __restrict__ R_true, const float* __restrict__ t_true,
    const float* __restrict__ temp,
    float4* __restrict__ Pg)
{
    __shared__ float4 Q[QCH];             // 8 KB
    __shared__ float  MLp[NWAVE][ROWS];   // 16 KB: pass-1 minima, then L-partials
    __shared__ float  Sp[NWAVE][ROWS];    // 16 KB
    __shared__ float  shl[ROWS];          // 2 KB (uniform shift per row, A-units)
    __shared__ float  pwl[ROWS];          // 2 KB (c*|p|^2 per row)

    const int tid  = threadIdx.x;
    const int wave = tid >> 6;
    const int lane = tid & 63;
    const int x    = blockIdx.x;
    const int ms   = x & 7;
    const int rg   = (x >> 3) & 7;        // 8 row-groups of 512 rows
    const int b    = x >> 6;

    const float T   = temp[0];
    const float c   = LOG2E / T;
    const float m2c = -2.0f * c;

    // ---- stage 512 transformed+prescaled q's (threads 0..255, 2 each) ----
    if (tid < QCH / 2) {
        const float g00 = R_true[b*9+0], g01 = R_true[b*9+1], g02 = R_true[b*9+2];
        const float g10 = R_true[b*9+3], g11 = R_true[b*9+4], g12 = R_true[b*9+5];
        const float g20 = R_true[b*9+6], g21 = R_true[b*9+7], g22 = R_true[b*9+8];
        const float u0  = t_true[b*3+0], u1 = t_true[b*3+1], u2 = t_true[b*3+2];
        const float2* xt = (const float2*)(X_true + ((size_t)b * M_ + ms * QCH) * 3);
        const float2 f0 = xt[3*tid+0], f1 = xt[3*tid+1], f2 = xt[3*tid+2];
        {
            const float y0 = fmaf(g00, f0.x, fmaf(g01, f0.y, fmaf(g02, f1.x, u0)));
            const float y1 = fmaf(g10, f0.x, fmaf(g11, f0.y, fmaf(g12, f1.x, u1)));
            const float y2 = fmaf(g20, f0.x, fmaf(g21, f0.y, fmaf(g22, f1.x, u2)));
            const float nn = fmaf(y0, y0, fmaf(y1, y1, y2 * y2));
            Q[2*tid]   = make_float4(m2c*y0, m2c*y1, m2c*y2, c*nn);
        }
        {
            const float y0 = fmaf(g00, f1.y, fmaf(g01, f2.x, fmaf(g02, f2.y, u0)));
            const float y1 = fmaf(g10, f1.y, fmaf(g11, f2.x, fmaf(g12, f2.y, u1)));
            const float y2 = fmaf(g20, f1.y, fmaf(g21, f2.x, fmaf(g22, f2.y, u2)));
            const float nn = fmaf(y0, y0, fmaf(y1, y1, y2 * y2));
            Q[2*tid+1] = make_float4(m2c*y0, m2c*y1, m2c*y2, c*nn);
        }
    }

    // ---- my 8 rows: transform, pack into float2 pairs ----
    v2f px2[4], py2[4], pz2[4];
    {
        const float h00 = R_pred[b*9+0], h01 = R_pred[b*9+1], h02 = R_pred[b*9+2];
        const float h10 = R_pred[b*9+3], h11 = R_pred[b*9+4], h12 = R_pred[b*9+5];
        const float h20 = R_pred[b*9+6], h21 = R_pred[b*9+7], h22 = R_pred[b*9+8];
        const float v0 = t_pred[b*3+0], v1 = t_pred[b*3+1], v2 = t_pred[b*3+2];
        const float4* xp = (const float4*)(X_pred + ((size_t)b * N_ + rg * ROWS + lane * 8) * 3);
        const float4 a0 = xp[0], a1 = xp[1], a2 = xp[2];
        const float4 a3 = xp[3], a4 = xp[4], a5 = xp[5];
        const float rx[8] = {a0.x, a0.w, a1.z, a2.y, a3.x, a3.w, a4.z, a5.y};
        const float ry[8] = {a0.y, a1.x, a1.w, a2.z, a3.y, a4.x, a4.w, a5.z};
        const float rz[8] = {a0.z, a1.y, a2.x, a2.w, a3.z, a4.y, a5.x, a5.w};
        #pragma unroll
        for (int j = 0; j < 8; ++j) {
            const float ppx = fmaf(h00, rx[j], fmaf(h01, ry[j], fmaf(h02, rz[j], v0)));
            const float ppy = fmaf(h10, rx[j], fmaf(h11, ry[j], fmaf(h12, rz[j], v1)));
            const float ppz = fmaf(h20, rx[j], fmaf(h21, ry[j], fmaf(h22, rz[j], v2)));
            px2[j >> 1][j & 1] = ppx;
            py2[j >> 1][j & 1] = ppy;
            pz2[j >> 1][j & 1] = ppz;
            // all waves write the same value (rows block-redundant) - benign
            pwl[8*lane + j] = c * fmaf(ppx, ppx, fmaf(ppy, ppy, ppz * ppz));
        }
    }

    __syncthreads();

    const float4* __restrict__ Qw = Q + wave * WQ;

    // ---- pass 1: packed min of A over my 64-q slice ----
    v2f mA2[4] = {{BIGF, BIGF}, {BIGF, BIGF}, {BIGF, BIGF}, {BIGF, BIGF}};
    #pragma unroll 4
    for (int k = 0; k < WQ; ++k) {
        const float4 q = Qw[k];   // ds_read_b128, wave-uniform broadcast
        const v2f qx = {q.x, q.x}, qy = {q.y, q.y}, qz = {q.z, q.z}, qw = {q.w, q.w};
        #pragma unroll
        for (int j = 0; j < 4; ++j) {
            const v2f A = qx * px2[j] + (qy * py2[j] + (qz * pz2[j] + qw));
            mA2[j] = __builtin_elementwise_min(mA2[j], A);
        }
    }
    #pragma unroll
    for (int j = 0; j < 4; ++j) {
        MLp[wave][8*lane + 2*j]     = mA2[j].x;
        MLp[wave][8*lane + 2*j + 1] = mA2[j].y;
    }
    __syncthreads();

    // ---- block-uniform per-row shift (A-units) ----
    {
        float m = MLp[0][tid];
        #pragma unroll
        for (int w2 = 1; w2 < NWAVE; ++w2) m = fminf(m, MLp[w2][tid]);
        shl[tid] = m;
    }
    __syncthreads();

    v2f sh2[4];
    {
        const float4 s0 = *(const float4*)&shl[8*lane];
        const float4 s1 = *(const float4*)&shl[8*lane + 4];
        sh2[0] = (v2f){s0.x, s0.y};  sh2[1] = (v2f){s0.z, s0.w};
        sh2[2] = (v2f){s1.x, s1.y};  sh2[3] = (v2f){s1.z, s1.w};
    }

    // ---- pass 2: packed shifted sums ----
    v2f L2[4]  = {{0.f,0.f},{0.f,0.f},{0.f,0.f},{0.f,0.f}};
    v2f SA2[4] = {{0.f,0.f},{0.f,0.f},{0.f,0.f},{0.f,0.f}};
    #pragma unroll 4
    for (int k = 0; k < WQ; ++k) {
        const float4 q = Qw[k];
        const v2f qx = {q.x, q.x}, qy = {q.y, q.y}, qz = {q.z, q.z}, qw = {q.w, q.w};
        #pragma unroll
        for (int j = 0; j < 4; ++j) {
            const v2f A   = qx * px2[j] + (qy * py2[j] + (qz * pz2[j] + qw));
            const v2f arg = sh2[j] - A;                       // <= 0
            const v2f w   = {__builtin_amdgcn_exp2f(arg.x),
                             __builtin_amdgcn_exp2f(arg.y)};  // chunk-min -> 1
            L2[j]  += w;
            SA2[j]  = w * arg + SA2[j];                       // Sum w*(m_d - d)
        }
    }
    #pragma unroll
    for (int j = 0; j < 4; ++j) {
        MLp[wave][8*lane + 2*j]     = L2[j].x;
        MLp[wave][8*lane + 2*j + 1] = L2[j].y;
        Sp[wave][8*lane + 2*j]      = SA2[j].x;
        Sp[wave][8*lane + 2*j + 1]  = SA2[j].y;
    }
    __syncthreads();

    // ---- merge 8 wave-partials per row (same shift -> plain adds) ----
    {
        float Lr = 0.0f, Sr = 0.0f;
        #pragma unroll
        for (int w2 = 0; w2 < NWAVE; ++w2) { Lr += MLp[w2][tid]; Sr += Sp[w2][tid]; }
        const size_t row = (size_t)b * N_ + rg * ROWS + tid;
        // m_d = chunk-min of d = minA + pw (d-units); L = sum exp2(m_d - d);
        // SA = sum w*(m_d - d)
        Pg[row * MSPL + ms] = make_float4(shl[tid] + pwl[tid], Lr, Sr, 0.0f);
    }
}

__global__ __launch_bounds__(256) void softfape_finalize(
    const float4* __restrict__ Pg, const float* __restrict__ temp,
    float* __restrict__ out)
{
    __shared__ float ws4[4];
    const int tid = threadIdx.x;
    const size_t row = (size_t)blockIdx.x * 256 + tid;

    float4 P[MSPL];
    #pragma unroll
    for (int i = 0; i < MSPL; ++i) P[i] = Pg[row * MSPL + i];

    float m = P[0].x;
    #pragma unroll
    for (int i = 1; i < MSPL; ++i) m = fminf(m, P[i].x);

    float L = 0.0f, SA = 0.0f;
    #pragma unroll
    for (int i = 0; i < MSPL; ++i) {
        const float dm = m - P[i].x;                    // <= 0
        const float f  = __builtin_amdgcn_exp2f(dm);    // global-min chunk -> 1
        L  = fmaf(P[i].y, f, L);
        SA = fmaf(f, fmaf(dm, P[i].y, P[i].z), SA);
    }
    float wd = m - SA / L;   // = c * weighted_distance(row); L >= 1 guaranteed

    wd += __shfl_xor(wd, 1);  wd += __shfl_xor(wd, 2);  wd += __shfl_xor(wd, 4);
    wd += __shfl_xor(wd, 8);  wd += __shfl_xor(wd, 16); wd += __shfl_xor(wd, 32);
    if ((tid & 63) == 0) ws4[tid >> 6] = wd;
    __syncthreads();
    if (tid == 0) {
        const float s = ws4[0] + ws4[1] + ws4[2] + ws4[3];
        const float scale = temp[0] * LN2 / ((float)B_ * (float)N_);  // 1/c, mean
        atomicAdd(out, s * scale);
    }
}

extern "C" void kernel_launch(void* const* d_in, const int* in_sizes, int n_in,
                              void* d_out, int out_size, void* d_ws, size_t ws_size,
                              hipStream_t stream) {
    const float* X_pred = (const float*)d_in[0];
    const float* X_true = (const float*)d_in[1];
    const float* R_pred = (const float*)d_in[2];
    const float* t_pred = (const float*)d_in[3];
    const float* R_true = (const float*)d_in[4];
    const float* t_true = (const float*)d_in[5];
    const float* temp   = (const float*)d_in[6];
    float* out = (float*)d_out;

    float4* Pg = (float4*)d_ws;   // B*N*MSPL float4 = 4 MB, fully overwritten

    hipMemsetAsync(out, 0, sizeof(float), stream);

    softfape_main<<<dim3(B_ * 8 * MSPL), BLOCK, 0, stream>>>(
        X_pred, X_true, R_pred, t_pred, R_true, t_true, temp, Pg);

    softfape_finalize<<<dim3((B_ * N_) / 256), 256, 0, stream>>>(Pg, temp, out);
}